// Round 1
// baseline (411.754 us; speedup 1.0000x reference)
//
#include <hip/hip_runtime.h>

#define BN 4
#define LN 1024
#define SN 1024
#define HN 8
#define EN 64
#define OFF_ATT (BN * LN * HN * EN)
#define OFF_ENT (OFF_ATT + BN * HN * LN * SN)

// blockIdx.x encodes (lbHi, b, lbLo) so that the 4 batch-siblings of an
// (h, l-tile) are 8 blocks apart -> same XCD under round-robin -> phi/u
// slices stay L2-hot across their 4x re-read.
__device__ __forceinline__ void decode_block(int x, int& b, int& lb) {
  int lbLo = x & 7;
  b = (x >> 3) & 3;
  lb = (x >> 5) * 8 + lbLo;
}

__device__ __forceinline__ float wave_max(float v) {
#pragma unroll
  for (int o = 32; o >= 1; o >>= 1) v = fmaxf(v, __shfl_xor(v, o, 64));
  return v;
}
__device__ __forceinline__ float wave_sum(float v) {
#pragma unroll
  for (int o = 32; o >= 1; o >>= 1) v += __shfl_xor(v, o, 64);
  return v;
}

// Block = 256 threads = 4 waves; block handles 16 query rows of one (b,h).
// Wave w owns rows lw..lw+3; lane c owns s = j*64 + c for j=0..15.
__global__ __launch_bounds__(256) void k_scores(
    const float* __restrict__ q, const float* __restrict__ kk,
    const float* __restrict__ pos, const float* __restrict__ phi,
    const float* __restrict__ u, const float* __restrict__ p_logtau,
    const float* __restrict__ p_thresh, const int* __restrict__ p_causal,
    float* __restrict__ out) {
  int b, lb;
  decode_block(blockIdx.x, b, lb);
  const int h = blockIdx.y;
  const int tid = threadIdx.x;
  const int w = __builtin_amdgcn_readfirstlane(tid >> 6);  // force wave-uniform
  const int c = tid & 63;
  const int lw = lb * 16 + w * 4;

  // K tile staged transposed: float4 granule g = e4*64 + (s ^ (e4&7))
  __shared__ float lds_k[64 * 64];

  const float tau = fminf(fmaxf(expf(p_logtau[0]), 0.1f), 5.0f);
  const float rtau = 1.0f / tau;
  const float thr = fminf(fmaxf(p_thresh[0], 0.01f), 0.99f);
  const int causal = p_causal[0];

  float sc[4][16];  // [row][s-tile] raw dot products, then scores, then exp()

  const float* qbase = q + (((size_t)b * LN + lw) * HN + h) * EN;  // uniform

#pragma unroll
  for (int t = 0; t < 16; ++t) {
    // ---- stage K tile (64 s x 64 e), coalesced global read, swizzled LDS write
#pragma unroll
    for (int rep = 0; rep < 4; ++rep) {
      int idx = rep * 256 + tid;
      int sl = idx >> 4;   // 0..63
      int e4 = idx & 15;   // float4 column
      float4 kv = *(const float4*)(kk +
          (((size_t)b * SN + t * 64 + sl) * HN + h) * EN + e4 * 4);
      *(float4*)(lds_k + (e4 * 64 + (sl ^ (e4 & 7))) * 4) = kv;
    }
    __syncthreads();

    // ---- QK: k per-lane from LDS (b128, conflict-free), q via scalar loads
    float a0 = 0.f, a1 = 0.f, a2 = 0.f, a3 = 0.f;
    for (int e4 = 0; e4 < 16; ++e4) {
      float4 kv = *(const float4*)(lds_k + (e4 * 64 + (c ^ (e4 & 7))) * 4);
      const float* q0 = qbase + e4 * 4;
      const float* q1 = q0 + HN * EN;
      const float* q2 = q0 + 2 * HN * EN;
      const float* q3 = q0 + 3 * HN * EN;
      a0 = fmaf(q0[0], kv.x, fmaf(q0[1], kv.y, fmaf(q0[2], kv.z, fmaf(q0[3], kv.w, a0))));
      a1 = fmaf(q1[0], kv.x, fmaf(q1[1], kv.y, fmaf(q1[2], kv.z, fmaf(q1[3], kv.w, a1))));
      a2 = fmaf(q2[0], kv.x, fmaf(q2[1], kv.y, fmaf(q2[2], kv.z, fmaf(q2[3], kv.w, a2))));
      a3 = fmaf(q3[0], kv.x, fmaf(q3[1], kv.y, fmaf(q3[2], kv.z, fmaf(q3[3], kv.w, a3))));
    }
    sc[0][t] = a0; sc[1][t] = a1; sc[2][t] = a2; sc[3][t] = a3;
    __syncthreads();
  }

  // ---- masks + softmax + entropy + att write
  const float* posb = pos + b * LN;
  float ps[16];
#pragma unroll
  for (int j = 0; j < 16; ++j) ps[j] = posb[j * 64 + c];

#pragma unroll
  for (int r = 0; r < 4; ++r) {
    const int l = lw + r;
    const float plr = posb[l];
    const float* ub = u + ((size_t)h * LN + l) * SN;
    const float* pb = phi + ((size_t)h * LN + l) * SN;
    float mx = -3.0e38f;
#pragma unroll
    for (int j = 0; j < 16; ++j) {
      const int s = j * 64 + c;
      float uu = ub[s];
      float ph = pb[s];
      // gumbel = log(u+eps) - log(1-u+eps) = log((u+eps)/(1-u+eps))
      float g = __logf(__fdividef(uu + 1e-8f, 1.0f - uu + 1e-8f));
      float z = (g + ph) * rtau;
      float sig = __fdividef(1.0f, 1.0f + __expf(-z));
      float pm = -10000.0f * fmaxf(thr - sig, 0.0f);
      float valv = (sc[r][j] + pm) * 0.125f;
      bool maskd = (causal != 0) && (ps[j] > plr);
      valv = maskd ? -1.0e30f : valv;
      sc[r][j] = valv;
      mx = fmaxf(mx, valv);
    }
    mx = wave_max(mx);
    float zz = 0.f, ee = 0.f;
#pragma unroll
    for (int j = 0; j < 16; ++j) {
      float tt = sc[r][j] - mx;
      float ex = __expf(tt);
      zz += ex;
      ee = fmaf(ex, fmaxf(tt, -88.0f), ee);  // guard 0 * -1e30 = NaN
      sc[r][j] = ex;
    }
    zz = wave_sum(zz);
    ee = wave_sum(ee);
    const float rz = __fdividef(1.0f, zz);
    float* ab = out + OFF_ATT + (((size_t)b * HN + h) * LN + l) * SN;
#pragma unroll
    for (int j = 0; j < 16; ++j) ab[j * 64 + c] = sc[r][j] * rz;
    // entropy = log Z - (1/Z) * sum e_i * (x_i - m)
    if (c == 0) out[OFF_ENT + ((size_t)b * HN + h) * LN + l] = __logf(zz) - ee * rz;
  }
}

// PV: V[b,l,h,:] = sum_s att[b,h,l,s] * v[b,s,h,:]
// Wave owns 4 rows; lane: dq = c&15 (d = dq*4..dq*4+3), sg = c>>4 covers s%4.
__global__ __launch_bounds__(256) void k_pv(const float* __restrict__ val,
                                            const float* __restrict__ att,
                                            float* __restrict__ out) {
  int b, lb;
  decode_block(blockIdx.x, b, lb);
  const int h = blockIdx.y;
  const int tid = threadIdx.x;
  const int w = tid >> 6;
  const int c = tid & 63;
  const int dq = c & 15;
  const int sg = c >> 4;
  const int l = lb * 16 + w * 4;

  const float* ab = att + (((size_t)b * HN + h) * LN + l) * SN;
  const float* vb = val + ((size_t)b * SN * HN + h) * EN + dq * 4;

  float4 acc[4];
#pragma unroll
  for (int r = 0; r < 4; ++r) acc[r] = make_float4(0.f, 0.f, 0.f, 0.f);

  for (int st = 0; st < 256; ++st) {
    int s = st * 4 + sg;
    float4 v4 = *(const float4*)(vb + (size_t)s * (HN * EN));
#pragma unroll
    for (int r = 0; r < 4; ++r) {
      float p = ab[r * SN + s];  // 16-lane broadcast load, L1-hot
      acc[r].x = fmaf(p, v4.x, acc[r].x);
      acc[r].y = fmaf(p, v4.y, acc[r].y);
      acc[r].z = fmaf(p, v4.z, acc[r].z);
      acc[r].w = fmaf(p, v4.w, acc[r].w);
    }
  }

  // reduce the 4 s-subgroups (lanes c, c^16, c^32, c^48)
#pragma unroll
  for (int r = 0; r < 4; ++r) {
#pragma unroll
    for (int o = 16; o <= 32; o <<= 1) {
      acc[r].x += __shfl_xor(acc[r].x, o, 64);
      acc[r].y += __shfl_xor(acc[r].y, o, 64);
      acc[r].z += __shfl_xor(acc[r].z, o, 64);
      acc[r].w += __shfl_xor(acc[r].w, o, 64);
    }
  }
  if (c < 16) {
#pragma unroll
    for (int r = 0; r < 4; ++r)
      *(float4*)(out + (((size_t)b * LN + l + r) * HN + h) * EN + c * 4) = acc[r];
  }
}

extern "C" void kernel_launch(void* const* d_in, const int* in_sizes, int n_in,
                              void* d_out, int out_size, void* d_ws, size_t ws_size,
                              hipStream_t stream) {
  (void)in_sizes; (void)n_in; (void)out_size; (void)d_ws; (void)ws_size;
  const float* q   = (const float*)d_in[0];
  const float* k   = (const float*)d_in[1];
  const float* v   = (const float*)d_in[2];
  const float* pos = (const float*)d_in[3];
  const float* phi = (const float*)d_in[4];
  const float* u   = (const float*)d_in[5];
  const float* lt  = (const float*)d_in[6];
  const float* th  = (const float*)d_in[7];
  const int*   cm  = (const int*)d_in[8];
  float* out = (float*)d_out;

  dim3 grid(256, 8, 1), blk(256, 1, 1);
  k_scores<<<grid, blk, 0, stream>>>(q, k, pos, phi, u, lt, th, cm, out);
  k_pv<<<grid, blk, 0, stream>>>(v, out + OFF_ATT, out);
}

// Round 2
// 262.071 us; speedup vs baseline: 1.5712x; 1.5712x over previous
//
#include <hip/hip_runtime.h>

#define BN 4
#define LN 1024
#define SN 1024
#define HN 8
#define EN 64
#define OFF_ATT (BN * LN * HN * EN)
#define OFF_ENT (OFF_ATT + BN * HN * LN * SN)

typedef __attribute__((ext_vector_type(8))) __bf16 bf16x8;
typedef __attribute__((ext_vector_type(4))) float f32x4;
typedef __attribute__((ext_vector_type(4))) unsigned int uint4v;
typedef __attribute__((ext_vector_type(2))) unsigned int uint2v;

// blockIdx.x encodes (lbHi, b, lbLo): batch-siblings of an (h,l-tile) are 8
// blocks apart -> same XCD under round-robin -> phi/u slices L2-hot across
// their 4x re-read (phi/u don't depend on b).
__device__ __forceinline__ void decode_block(int x, int& b, int& lb) {
  int lbLo = x & 7;
  b = (x >> 3) & 3;
  lb = (x >> 5) * 8 + lbLo;
}

// convert 8 consecutive floats to packed bf16 hi + lo (truncation split:
// lo = bf16(x - float(hi)); residual ~2^-16 relative)
__device__ __forceinline__ void cvt8(const float* p, uint4v& hv, uint4v& lv) {
  float4 a = *(const float4*)p;
  float4 bq = *(const float4*)(p + 4);
  float x[8] = {a.x, a.y, a.z, a.w, bq.x, bq.y, bq.z, bq.w};
  unsigned int h[8], lo[8];
#pragma unroll
  for (int i = 0; i < 8; ++i) {
    unsigned int ub = __float_as_uint(x[i]);
    h[i] = ub >> 16;
    float lf = x[i] - __uint_as_float(ub & 0xffff0000u);
    lo[i] = __float_as_uint(lf) >> 16;
  }
  hv = uint4v{h[0] | (h[1] << 16), h[2] | (h[3] << 16),
              h[4] | (h[5] << 16), h[6] | (h[7] << 16)};
  lv = uint4v{lo[0] | (lo[1] << 16), lo[2] | (lo[3] << 16),
              lo[4] | (lo[5] << 16), lo[6] | (lo[7] << 16)};
}

// Block = 256 threads = 4 waves; handles 16 query rows of one (b,h).
// All waves share the 16 q-rows; s-space is split 4 ways (wave w owns
// s%128 in [w*32, w*32+32) of each 128-s chunk).
// MFMA 16x16x32 bf16, hi/lo split (3 mfma per K=32 sub-chunk).
__global__ __launch_bounds__(256, 4) void k_scores(
    const float* __restrict__ q, const float* __restrict__ kk,
    const float* __restrict__ pos, const float* __restrict__ phi,
    const float* __restrict__ u, const float* __restrict__ p_logtau,
    const float* __restrict__ p_thresh, const int* __restrict__ p_causal,
    float* __restrict__ out) {
  int b, lb;
  decode_block(blockIdx.x, b, lb);
  const int h = blockIdx.y;
  const int tid = threadIdx.x;
  const int w = tid >> 6;
  const int c = tid & 63;
  const int cl = c & 15;   // lane within 16-group
  const int cg = c >> 4;   // 16-group index

  // K chunk staged as packed bf16: hi at [0,16KB), lo at [16KB,32KB).
  // Row = 128B (64 bf16); 16B granule g stored at (g ^ (row&7)).
  __shared__ unsigned int kbuf[8192];
  __shared__ float red[4][3][16];  // [wave][max/z/e][row]

  const float tau = fminf(fmaxf(__expf(p_logtau[0]), 0.1f), 5.0f);
  const float rtau = 1.0f / tau;
  const float thr = fminf(fmaxf(p_thresh[0], 0.01f), 0.99f);
  const int causal = p_causal[0];

  // ---- Q fragments (held in registers for whole kernel).
  // A-frag lane mapping (16x16x32): m = lane&15, k = (lane>>4)*8 + j.
  uint4v qh[2], ql[2];
#pragma unroll
  for (int cc = 0; cc < 2; ++cc) {
    const float* qp = q + (((size_t)b * LN + lb * 16 + cl) * HN + h) * EN +
                      cc * 32 + cg * 8;
    cvt8(qp, qh[cc], ql[cc]);
  }

  f32x4 accs[16];  // [s-tile] -> 4 q-rows x 1 s-col per lane

#pragma unroll
  for (int chunk = 0; chunk < 8; ++chunk) {
    // ---- stage 128 K-rows (fp32 -> bf16 hi/lo, swizzled)
#pragma unroll
    for (int rep = 0; rep < 8; ++rep) {
      int idx = rep * 256 + tid;
      int e4 = idx & 15;
      int sl = idx >> 4;  // 0..127
      const float* kp = kk + (((size_t)b * SN + chunk * 128 + sl) * HN + h) * EN + e4 * 4;
      float4 kv = *(const float4*)kp;
      unsigned int u0 = __float_as_uint(kv.x), u1 = __float_as_uint(kv.y);
      unsigned int u2 = __float_as_uint(kv.z), u3 = __float_as_uint(kv.w);
      unsigned int hi01 = (u0 >> 16) | (u1 & 0xffff0000u);
      unsigned int hi23 = (u2 >> 16) | (u3 & 0xffff0000u);
      float l0 = kv.x - __uint_as_float(u0 & 0xffff0000u);
      float l1 = kv.y - __uint_as_float(u1 & 0xffff0000u);
      float l2 = kv.z - __uint_as_float(u2 & 0xffff0000u);
      float l3 = kv.w - __uint_as_float(u3 & 0xffff0000u);
      unsigned int lo01 = (__float_as_uint(l0) >> 16) | (__float_as_uint(l1) & 0xffff0000u);
      unsigned int lo23 = (__float_as_uint(l2) >> 16) | (__float_as_uint(l3) & 0xffff0000u);
      int byteoff = sl * 128 + (((e4 >> 1) ^ (sl & 7)) * 16) + (e4 & 1) * 8;
      *(uint2v*)((char*)kbuf + byteoff) = uint2v{hi01, hi23};
      *(uint2v*)((char*)kbuf + 16384 + byteoff) = uint2v{lo01, lo23};
    }
    __syncthreads();

    // ---- MFMA: 2 s-tiles per wave per chunk
#pragma unroll
    for (int t = 0; t < 2; ++t) {
      int row = w * 32 + t * 16 + cl;  // K row (local to chunk) = s col
      f32x4 acc = f32x4{0.f, 0.f, 0.f, 0.f};
#pragma unroll
      for (int cc = 0; cc < 2; ++cc) {
        int g = (cc * 4 + cg) ^ (row & 7);
        int off = row * 128 + g * 16;
        bf16x8 bh = __builtin_bit_cast(bf16x8, *(const uint4v*)((const char*)kbuf + off));
        bf16x8 bl = __builtin_bit_cast(bf16x8, *(const uint4v*)((const char*)kbuf + 16384 + off));
        bf16x8 ah = __builtin_bit_cast(bf16x8, qh[cc]);
        bf16x8 al = __builtin_bit_cast(bf16x8, ql[cc]);
        acc = __builtin_amdgcn_mfma_f32_16x16x32_bf16(ah, bh, acc, 0, 0, 0);
        acc = __builtin_amdgcn_mfma_f32_16x16x32_bf16(ah, bl, acc, 0, 0, 0);
        acc = __builtin_amdgcn_mfma_f32_16x16x32_bf16(al, bh, acc, 0, 0, 0);
      }
      accs[chunk * 2 + t] = acc;
    }
    __syncthreads();
  }

  // ---- masks + softmax + entropy + att write
  // D layout: lane holds q-rows (cg*4 + r), s-col per tile = tile_s_base + cl.
  const float* posb = pos + b * LN;
  float mx[4];
#pragma unroll
  for (int r = 0; r < 4; ++r) {
    const int row_l = cg * 4 + r;
    const int l = lb * 16 + row_l;
    const float plr = posb[l];
    const float* ub = u + ((size_t)h * LN + l) * SN;
    const float* pb = phi + ((size_t)h * LN + l) * SN;
    float m = -3.0e38f;
#pragma unroll
    for (int tg = 0; tg < 16; ++tg) {
      const int s = (tg >> 1) * 128 + w * 32 + (tg & 1) * 16 + cl;
      float uu = ub[s];
      float ph = pb[s];
      float g = __logf(__fdividef(uu + 1e-8f, 1.0f - uu + 1e-8f));
      float z = (g + ph) * rtau;
      float sig = __fdividef(1.0f, 1.0f + __expf(-z));
      float pm = -10000.0f * fmaxf(thr - sig, 0.0f);
      float valv = (accs[tg][r] + pm) * 0.125f;
      bool maskd = (causal != 0) && (posb[s] > plr);
      valv = maskd ? -1.0e30f : valv;
      accs[tg][r] = valv;
      m = fmaxf(m, valv);
    }
    mx[r] = m;
  }
  // 16-lane group reduce (rows live across cl)
#pragma unroll
  for (int r = 0; r < 4; ++r) {
#pragma unroll
    for (int o = 1; o < 16; o <<= 1) mx[r] = fmaxf(mx[r], __shfl_xor(mx[r], o, 64));
  }
  if (cl == 0) {
#pragma unroll
    for (int r = 0; r < 4; ++r) red[w][0][cg * 4 + r] = mx[r];
  }
  __syncthreads();
  float bmx[4], zz[4], ee[4];
#pragma unroll
  for (int r = 0; r < 4; ++r) {
    const int row_l = cg * 4 + r;
    bmx[r] = fmaxf(fmaxf(red[0][0][row_l], red[1][0][row_l]),
                   fmaxf(red[2][0][row_l], red[3][0][row_l]));
    float z = 0.f, e = 0.f;
#pragma unroll
    for (int tg = 0; tg < 16; ++tg) {
      float tt = accs[tg][r] - bmx[r];
      float ex = __expf(tt);
      z += ex;
      e = fmaf(ex, fmaxf(tt, -88.0f), e);  // guard 0 * -1e30
      accs[tg][r] = ex;
    }
    zz[r] = z;
    ee[r] = e;
  }
#pragma unroll
  for (int r = 0; r < 4; ++r) {
#pragma unroll
    for (int o = 1; o < 16; o <<= 1) {
      zz[r] += __shfl_xor(zz[r], o, 64);
      ee[r] += __shfl_xor(ee[r], o, 64);
    }
  }
  __syncthreads();  // red[..][0] no longer needed
  if (cl == 0) {
#pragma unroll
    for (int r = 0; r < 4; ++r) {
      red[w][1][cg * 4 + r] = zz[r];
      red[w][2][cg * 4 + r] = ee[r];
    }
  }
  __syncthreads();
#pragma unroll
  for (int r = 0; r < 4; ++r) {
    const int row_l = cg * 4 + r;
    const int l = lb * 16 + row_l;
    float Z = red[0][1][row_l] + red[1][1][row_l] + red[2][1][row_l] + red[3][1][row_l];
    float E = red[0][2][row_l] + red[1][2][row_l] + red[2][2][row_l] + red[3][2][row_l];
    const float rz = __fdividef(1.0f, Z);
    float* ab = out + OFF_ATT + (((size_t)b * HN + h) * LN + l) * SN;
#pragma unroll
    for (int tg = 0; tg < 16; ++tg) {
      const int s = (tg >> 1) * 128 + w * 32 + (tg & 1) * 16 + cl;
      ab[s] = accs[tg][r] * rz;
    }
    if (w == 0 && cl == 0)
      out[OFF_ENT + ((size_t)b * HN + h) * LN + l] = __logf(Z) - E * rz;
  }
}

// PV: V[b,l,h,:] = sum_s att[b,h,l,s] * v[b,s,h,:]
__global__ __launch_bounds__(256) void k_pv(const float* __restrict__ val,
                                            const float* __restrict__ att,
                                            float* __restrict__ out) {
  int b, lb;
  decode_block(blockIdx.x, b, lb);
  const int h = blockIdx.y;
  const int tid = threadIdx.x;
  const int w = tid >> 6;
  const int c = tid & 63;
  const int dq = c & 15;
  const int sg = c >> 4;
  const int l = lb * 16 + w * 4;

  const float* ab = att + (((size_t)b * HN + h) * LN + l) * SN;
  const float* vb = val + ((size_t)b * SN * HN + h) * EN + dq * 4;

  float4 acc[4];
#pragma unroll
  for (int r = 0; r < 4; ++r) acc[r] = make_float4(0.f, 0.f, 0.f, 0.f);

  for (int st = 0; st < 256; ++st) {
    int s = st * 4 + sg;
    float4 v4 = *(const float4*)(vb + (size_t)s * (HN * EN));
#pragma unroll
    for (int r = 0; r < 4; ++r) {
      float p = ab[r * SN + s];
      acc[r].x = fmaf(p, v4.x, acc[r].x);
      acc[r].y = fmaf(p, v4.y, acc[r].y);
      acc[r].z = fmaf(p, v4.z, acc[r].z);
      acc[r].w = fmaf(p, v4.w, acc[r].w);
    }
  }
#pragma unroll
  for (int r = 0; r < 4; ++r) {
#pragma unroll
    for (int o = 16; o <= 32; o <<= 1) {
      acc[r].x += __shfl_xor(acc[r].x, o, 64);
      acc[r].y += __shfl_xor(acc[r].y, o, 64);
      acc[r].z += __shfl_xor(acc[r].z, o, 64);
      acc[r].w += __shfl_xor(acc[r].w, o, 64);
    }
  }
  if (c < 16) {
#pragma unroll
    for (int r = 0; r < 4; ++r)
      *(float4*)(out + (((size_t)b * LN + l + r) * HN + h) * EN + c * 4) = acc[r];
  }
}

extern "C" void kernel_launch(void* const* d_in, const int* in_sizes, int n_in,
                              void* d_out, int out_size, void* d_ws, size_t ws_size,
                              hipStream_t stream) {
  (void)in_sizes; (void)n_in; (void)out_size; (void)d_ws; (void)ws_size;
  const float* q   = (const float*)d_in[0];
  const float* k   = (const float*)d_in[1];
  const float* v   = (const float*)d_in[2];
  const float* pos = (const float*)d_in[3];
  const float* phi = (const float*)d_in[4];
  const float* u   = (const float*)d_in[5];
  const float* lt  = (const float*)d_in[6];
  const float* th  = (const float*)d_in[7];
  const int*   cm  = (const int*)d_in[8];
  float* out = (float*)d_out;

  dim3 grid(256, 8, 1), blk(256, 1, 1);
  k_scores<<<grid, blk, 0, stream>>>(q, k, pos, phi, u, lt, th, cm, out);
  k_pv<<<grid, blk, 0, stream>>>(v, out + OFF_ATT, out);
}

// Round 3
// 260.731 us; speedup vs baseline: 1.5792x; 1.0051x over previous
//
#include <hip/hip_runtime.h>

#define BN 4
#define LN 1024
#define SN 1024
#define HN 8
#define EN 64
#define OFF_ATT (BN * LN * HN * EN)
#define OFF_ENT (OFF_ATT + BN * HN * LN * SN)

// workspace byte offsets
#define WS_MASK 0u
#define WS_KHI  33554432u                 // 8*1024*1024*4
#define WS_KLO  (WS_KHI + 4194304u)       // 4*8*1024*64*2
#define WS_VT   (WS_KLO + 4194304u)
#define WS_NEED (WS_VT + 4194304u)

typedef __attribute__((ext_vector_type(8))) __bf16 bf16x8;
typedef __attribute__((ext_vector_type(4))) float f32x4;
typedef __attribute__((ext_vector_type(4))) unsigned int uint4v;

// blockIdx.x encodes (lbHi, b, lbLo): batch-siblings of an (h,l-tile) are 8
// blocks apart -> same XCD under round-robin -> shared phi-mask slices L2-hot.
__device__ __forceinline__ void decode_block(int x, int& b, int& lb) {
  int lbLo = x & 7;
  b = (x >> 3) & 3;
  lb = (x >> 5) * 8 + lbLo;
}

// 8 consecutive floats -> packed bf16 hi + lo (trunc split)
__device__ __forceinline__ void cvt8(const float* p, uint4v& hv, uint4v& lv) {
  float4 a = *(const float4*)p;
  float4 bq = *(const float4*)(p + 4);
  float x[8] = {a.x, a.y, a.z, a.w, bq.x, bq.y, bq.z, bq.w};
  unsigned int h[8], lo[8];
#pragma unroll
  for (int i = 0; i < 8; ++i) {
    unsigned int ub = __float_as_uint(x[i]);
    h[i] = ub >> 16;
    float lf = x[i] - __uint_as_float(ub & 0xffff0000u);
    lo[i] = __float_as_uint(lf) >> 16;
  }
  hv = uint4v{h[0] | (h[1] << 16), h[2] | (h[3] << 16),
              h[4] | (h[5] << 16), h[6] | (h[7] << 16)};
  lv = uint4v{lo[0] | (lo[1] << 16), lo[2] | (lo[3] << 16),
              lo[4] | (lo[5] << 16), lo[6] | (lo[7] << 16)};
}

__device__ __forceinline__ uint4v pack8_trunc(float4 a, float4 b) {
  return uint4v{(__float_as_uint(a.x) >> 16) | (__float_as_uint(a.y) & 0xffff0000u),
                (__float_as_uint(a.z) >> 16) | (__float_as_uint(a.w) & 0xffff0000u),
                (__float_as_uint(b.x) >> 16) | (__float_as_uint(b.y) & 0xffff0000u),
                (__float_as_uint(b.z) >> 16) | (__float_as_uint(b.w) & 0xffff0000u)};
}

// ---------------- prep kernels ----------------

// phi-mask: pm = -10000*relu(thr - sigmoid((gumbel+phi)/tau)) * 0.125, fp32
__global__ __launch_bounds__(256) void k_mask_prep(
    const float* __restrict__ phi, const float* __restrict__ u,
    const float* __restrict__ p_logtau, const float* __restrict__ p_thresh,
    float* __restrict__ mw) {
  const float tau = fminf(fmaxf(__expf(p_logtau[0]), 0.1f), 5.0f);
  const float rtau = 1.0f / tau;
  const float thr = fminf(fmaxf(p_thresh[0], 0.01f), 0.99f);
  int idx = (blockIdx.x * 256 + threadIdx.x) * 4;
  float4 u4 = *(const float4*)(u + idx);
  float4 p4 = *(const float4*)(phi + idx);
  float r[4];
  float uu[4] = {u4.x, u4.y, u4.z, u4.w};
  float pp[4] = {p4.x, p4.y, p4.z, p4.w};
#pragma unroll
  for (int i = 0; i < 4; ++i) {
    float g = __logf(__fdividef(uu[i] + 1e-8f, 1.0f - uu[i] + 1e-8f));
    float z = (g + pp[i]) * rtau;
    float sig = __fdividef(1.0f, 1.0f + __expf(-z));
    r[i] = -10000.0f * fmaxf(thr - sig, 0.0f) * 0.125f;
  }
  *(float4*)(mw + idx) = float4{r[0], r[1], r[2], r[3]};
}

// K [b,s,h,e] fp32 -> khi/klo [b][h][s][e] bf16
__global__ __launch_bounds__(256) void k_kprep(const float* __restrict__ kk,
                                               unsigned short* __restrict__ khi,
                                               unsigned short* __restrict__ klo) {
  int gid = blockIdx.x * 256 + threadIdx.x;  // 262144 groups of 8 elements
  int e8 = gid & 7;
  int tmp = gid >> 3;
  int h = tmp & 7;
  int bs = tmp >> 3;
  int s = bs & 1023;
  int b = bs >> 10;
  const float* src = kk + (size_t)gid * 8;  // contiguous e within (b,s,h)
  uint4v hv, lv;
  cvt8(src, hv, lv);
  size_t off = (((size_t)(b * 8 + h) * 1024 + s) * 64) + e8 * 8;
  *(uint4v*)(khi + off) = hv;
  *(uint4v*)(klo + off) = lv;
}

// V [b,s,h,e] fp32 -> vT [b][h][e][s] bf16 (transpose)
__global__ __launch_bounds__(256) void k_vprep(const float* __restrict__ vv,
                                               unsigned short* __restrict__ vT) {
  int gid = blockIdx.x * 256 + threadIdx.x;  // 262144 groups of 8 s
  int s8 = gid & 127;
  int t1 = gid >> 7;
  int e = t1 & 63;
  int t2 = t1 >> 6;
  int h = t2 & 7;
  int b = t2 >> 3;
  float x[8];
#pragma unroll
  for (int j = 0; j < 8; ++j)
    x[j] = vv[((size_t)(b * 1024 + s8 * 8 + j) * 8 + h) * 64 + e];
  uint4v pv = pack8_trunc(float4{x[0], x[1], x[2], x[3]},
                          float4{x[4], x[5], x[6], x[7]});
  *(uint4v*)(vT + ((size_t)(b * 8 + h) * 64 + e) * 1024 + s8 * 8) = pv;
}

// ---------------- main kernels (ws path) ----------------

// Block = 4 waves, 16 q-rows of one (b,h). Swapped QK^T: D = K*Q so lane
// owns one q-row (col = lane&15) and 4 consecutive s per tile. Wave w owns
// s in [w*256, w*256+256) = 16 tiles. No LDS staging: K hi/lo fragments are
// direct 16B loads from pre-converted ws.
__global__ __launch_bounds__(256, 3) void k_scores2(
    const float* __restrict__ q, const unsigned short* __restrict__ khi,
    const unsigned short* __restrict__ klo, const float* __restrict__ mw,
    const float* __restrict__ pos, const int* __restrict__ p_causal,
    float* __restrict__ out) {
  int b, lb;
  decode_block(blockIdx.x, b, lb);
  const int h = blockIdx.y;
  const int tid = threadIdx.x;
  const int w = __builtin_amdgcn_readfirstlane(tid >> 6);
  const int c = tid & 63;
  const int cl = c & 15;
  const int cg = c >> 4;

  __shared__ float red0[4][16], redZ[4][16], redE[4][16];

  const int causal = p_causal[0];
  const int l = lb * 16 + cl;  // this lane's q-row

  // Q fragments (B operand): n = lane&15 = cl (q-row), k = cg*8+j
  uint4v qh[2], ql[2];
#pragma unroll
  for (int cc = 0; cc < 2; ++cc) {
    const float* qp = q + (((size_t)b * LN + l) * HN + h) * EN + cc * 32 + cg * 8;
    cvt8(qp, qh[cc], ql[cc]);
  }

  const size_t kbase = ((size_t)(b * 8 + h) * 1024) * 64;
  f32x4 accs[16];

#pragma unroll
  for (int tg = 0; tg < 16; ++tg) {
    const int row = w * 256 + tg * 16 + cl;  // K row (s) for A-frag
    const uint4v* ph0 = (const uint4v*)(khi + kbase + (size_t)row * 64);
    const uint4v* pl0 = (const uint4v*)(klo + kbase + (size_t)row * 64);
    f32x4 acc = f32x4{0.f, 0.f, 0.f, 0.f};
#pragma unroll
    for (int cc = 0; cc < 2; ++cc) {
      bf16x8 kh = __builtin_bit_cast(bf16x8, ph0[cc * 4 + cg]);
      bf16x8 kl = __builtin_bit_cast(bf16x8, pl0[cc * 4 + cg]);
      bf16x8 ah = __builtin_bit_cast(bf16x8, qh[cc]);
      bf16x8 al = __builtin_bit_cast(bf16x8, ql[cc]);
      acc = __builtin_amdgcn_mfma_f32_16x16x32_bf16(kh, ah, acc, 0, 0, 0);
      acc = __builtin_amdgcn_mfma_f32_16x16x32_bf16(kh, al, acc, 0, 0, 0);
      acc = __builtin_amdgcn_mfma_f32_16x16x32_bf16(kl, ah, acc, 0, 0, 0);
    }
    accs[tg] = acc;
  }

  // ---- mask + softmax + entropy + att (lane-local row, s contiguous x4)
  const float* posb = pos + b * LN;
  const float plr = posb[l];
  const float* mrow = mw + ((size_t)h * LN + l) * SN;

  float mx = -3.0e38f;
#pragma unroll
  for (int tg = 0; tg < 16; ++tg) {
    const int s0 = w * 256 + tg * 16 + cg * 4;
    float4 pm4 = *(const float4*)(mrow + s0);
    float4 po4 = *(const float4*)(posb + s0);
    float pmv[4] = {pm4.x, pm4.y, pm4.z, pm4.w};
    float pov[4] = {po4.x, po4.y, po4.z, po4.w};
#pragma unroll
    for (int r = 0; r < 4; ++r) {
      float v = fmaf(accs[tg][r], 0.125f, pmv[r]);
      bool maskd = (causal != 0) && (pov[r] > plr);
      v = maskd ? -1.0e30f : v;
      accs[tg][r] = v;
      mx = fmaxf(mx, v);
    }
  }
  // reduce over cg (lanes same cl), then cross-wave
  mx = fmaxf(mx, __shfl_xor(mx, 16, 64));
  mx = fmaxf(mx, __shfl_xor(mx, 32, 64));
  if (cg == 0) red0[w][cl] = mx;
  __syncthreads();
  const float bmx = fmaxf(fmaxf(red0[0][cl], red0[1][cl]),
                          fmaxf(red0[2][cl], red0[3][cl]));

  float zz = 0.f, ee = 0.f;
#pragma unroll
  for (int tg = 0; tg < 16; ++tg) {
#pragma unroll
    for (int r = 0; r < 4; ++r) {
      float tt = accs[tg][r] - bmx;
      float ex = __expf(tt);
      zz += ex;
      ee = fmaf(ex, fmaxf(tt, -88.0f), ee);  // guard 0 * -1e30
      accs[tg][r] = ex;
    }
  }
  zz += __shfl_xor(zz, 16, 64);
  zz += __shfl_xor(zz, 32, 64);
  ee += __shfl_xor(ee, 16, 64);
  ee += __shfl_xor(ee, 32, 64);
  if (cg == 0) { redZ[w][cl] = zz; redE[w][cl] = ee; }
  __syncthreads();
  const float Z = redZ[0][cl] + redZ[1][cl] + redZ[2][cl] + redZ[3][cl];
  const float E = redE[0][cl] + redE[1][cl] + redE[2][cl] + redE[3][cl];
  const float rz = __fdividef(1.0f, Z);

  float* ab = out + OFF_ATT + (((size_t)b * HN + h) * LN + l) * SN;
#pragma unroll
  for (int tg = 0; tg < 16; ++tg) {
    const int s0 = w * 256 + tg * 16 + cg * 4;
    *(float4*)(ab + s0) = float4{accs[tg][0] * rz, accs[tg][1] * rz,
                                 accs[tg][2] * rz, accs[tg][3] * rz};
  }
  if (w == 0 && cg == 0)
    out[OFF_ENT + ((size_t)b * HN + h) * LN + l] = __logf(Z) - E * rz;
}

// PV via MFMA: out[l,e] = sum_s att[l,s]*v[s,e]. A = att (m=l,k=s) packed
// bf16 in-reg from global; B = vT direct 16B loads. Wave w owns e-tile w.
__global__ __launch_bounds__(256) void k_pv2(const float* __restrict__ att,
                                             const unsigned short* __restrict__ vT,
                                             float* __restrict__ out) {
  int b, lb;
  decode_block(blockIdx.x, b, lb);
  const int h = blockIdx.y;
  const int tid = threadIdx.x;
  const int w = __builtin_amdgcn_readfirstlane(tid >> 6);
  const int c = tid & 63;
  const int cl = c & 15;
  const int cg = c >> 4;

  const float* ab = att + (((size_t)b * HN + h) * LN + lb * 16 + cl) * SN;
  const uint4v* vrow = (const uint4v*)(vT + ((size_t)(b * 8 + h) * 64 + w * 16 + cl) * 1024);

  f32x4 acc0 = f32x4{0.f, 0.f, 0.f, 0.f};
  f32x4 acc1 = f32x4{0.f, 0.f, 0.f, 0.f};
#pragma unroll
  for (int ks = 0; ks < 32; ++ks) {
    const int s = ks * 32 + cg * 8;
    float4 a0 = *(const float4*)(ab + s);
    float4 a1 = *(const float4*)(ab + s + 4);
    bf16x8 af = __builtin_bit_cast(bf16x8, pack8_trunc(a0, a1));
    bf16x8 bf = __builtin_bit_cast(bf16x8, vrow[ks * 4 + cg]);
    if (ks & 1)
      acc1 = __builtin_amdgcn_mfma_f32_16x16x32_bf16(af, bf, acc1, 0, 0, 0);
    else
      acc0 = __builtin_amdgcn_mfma_f32_16x16x32_bf16(af, bf, acc0, 0, 0, 0);
  }
  f32x4 acc = acc0 + acc1;
#pragma unroll
  for (int r = 0; r < 4; ++r)
    out[(((size_t)b * LN + lb * 16 + cg * 4 + r) * HN + h) * EN + w * 16 + cl] = acc[r];
}

// ---------------- fallback kernels (no ws) — proven R2 path ----------------

typedef __attribute__((ext_vector_type(2))) unsigned int uint2v;

__global__ __launch_bounds__(256, 4) void k_scores_fb(
    const float* __restrict__ q, const float* __restrict__ kk,
    const float* __restrict__ pos, const float* __restrict__ phi,
    const float* __restrict__ u, const float* __restrict__ p_logtau,
    const float* __restrict__ p_thresh, const int* __restrict__ p_causal,
    float* __restrict__ out) {
  int b, lb;
  decode_block(blockIdx.x, b, lb);
  const int h = blockIdx.y;
  const int tid = threadIdx.x;
  const int w = tid >> 6;
  const int c = tid & 63;
  const int cl = c & 15;
  const int cg = c >> 4;

  __shared__ unsigned int kbuf[8192];
  __shared__ float red[4][3][16];

  const float tau = fminf(fmaxf(__expf(p_logtau[0]), 0.1f), 5.0f);
  const float rtau = 1.0f / tau;
  const float thr = fminf(fmaxf(p_thresh[0], 0.01f), 0.99f);
  const int causal = p_causal[0];

  uint4v qh[2], ql[2];
#pragma unroll
  for (int cc = 0; cc < 2; ++cc) {
    const float* qp = q + (((size_t)b * LN + lb * 16 + cl) * HN + h) * EN + cc * 32 + cg * 8;
    cvt8(qp, qh[cc], ql[cc]);
  }

  f32x4 accs[16];
#pragma unroll
  for (int chunk = 0; chunk < 8; ++chunk) {
#pragma unroll
    for (int rep = 0; rep < 8; ++rep) {
      int idx = rep * 256 + tid;
      int e4 = idx & 15;
      int sl = idx >> 4;
      const float* kp = kk + (((size_t)b * SN + chunk * 128 + sl) * HN + h) * EN + e4 * 4;
      float4 kv = *(const float4*)kp;
      unsigned int u0 = __float_as_uint(kv.x), u1 = __float_as_uint(kv.y);
      unsigned int u2 = __float_as_uint(kv.z), u3 = __float_as_uint(kv.w);
      unsigned int hi01 = (u0 >> 16) | (u1 & 0xffff0000u);
      unsigned int hi23 = (u2 >> 16) | (u3 & 0xffff0000u);
      float l0 = kv.x - __uint_as_float(u0 & 0xffff0000u);
      float l1 = kv.y - __uint_as_float(u1 & 0xffff0000u);
      float l2 = kv.z - __uint_as_float(u2 & 0xffff0000u);
      float l3 = kv.w - __uint_as_float(u3 & 0xffff0000u);
      unsigned int lo01 = (__float_as_uint(l0) >> 16) | (__float_as_uint(l1) & 0xffff0000u);
      unsigned int lo23 = (__float_as_uint(l2) >> 16) | (__float_as_uint(l3) & 0xffff0000u);
      int byteoff = sl * 128 + (((e4 >> 1) ^ (sl & 7)) * 16) + (e4 & 1) * 8;
      *(uint2v*)((char*)kbuf + byteoff) = uint2v{hi01, hi23};
      *(uint2v*)((char*)kbuf + 16384 + byteoff) = uint2v{lo01, lo23};
    }
    __syncthreads();
#pragma unroll
    for (int t = 0; t < 2; ++t) {
      int row = w * 32 + t * 16 + cl;
      f32x4 acc = f32x4{0.f, 0.f, 0.f, 0.f};
#pragma unroll
      for (int cc = 0; cc < 2; ++cc) {
        int g = (cc * 4 + cg) ^ (row & 7);
        int off = row * 128 + g * 16;
        bf16x8 bh = __builtin_bit_cast(bf16x8, *(const uint4v*)((const char*)kbuf + off));
        bf16x8 bl = __builtin_bit_cast(bf16x8, *(const uint4v*)((const char*)kbuf + 16384 + off));
        bf16x8 ah = __builtin_bit_cast(bf16x8, qh[cc]);
        bf16x8 al = __builtin_bit_cast(bf16x8, ql[cc]);
        acc = __builtin_amdgcn_mfma_f32_16x16x32_bf16(ah, bh, acc, 0, 0, 0);
        acc = __builtin_amdgcn_mfma_f32_16x16x32_bf16(ah, bl, acc, 0, 0, 0);
        acc = __builtin_amdgcn_mfma_f32_16x16x32_bf16(al, bh, acc, 0, 0, 0);
      }
      accs[chunk * 2 + t] = acc;
    }
    __syncthreads();
  }

  const float* posb = pos + b * LN;
  float mx[4];
#pragma unroll
  for (int r = 0; r < 4; ++r) {
    const int row_l = cg * 4 + r;
    const int l = lb * 16 + row_l;
    const float plr = posb[l];
    const float* ub = u + ((size_t)h * LN + l) * SN;
    const float* pb = phi + ((size_t)h * LN + l) * SN;
    float m = -3.0e38f;
#pragma unroll
    for (int tg = 0; tg < 16; ++tg) {
      const int s = (tg >> 1) * 128 + w * 32 + (tg & 1) * 16 + cl;
      float uu = ub[s];
      float ph = pb[s];
      float g = __logf(__fdividef(uu + 1e-8f, 1.0f - uu + 1e-8f));
      float z = (g + ph) * rtau;
      float sig = __fdividef(1.0f, 1.0f + __expf(-z));
      float pm = -10000.0f * fmaxf(thr - sig, 0.0f);
      float valv = (accs[tg][r] + pm) * 0.125f;
      bool maskd = (causal != 0) && (posb[s] > plr);
      valv = maskd ? -1.0e30f : valv;
      accs[tg][r] = valv;
      m = fmaxf(m, valv);
    }
    mx[r] = m;
  }
#pragma unroll
  for (int r = 0; r < 4; ++r) {
#pragma unroll
    for (int o = 1; o < 16; o <<= 1) mx[r] = fmaxf(mx[r], __shfl_xor(mx[r], o, 64));
  }
  if (cl == 0) {
#pragma unroll
    for (int r = 0; r < 4; ++r) red[w][0][cg * 4 + r] = mx[r];
  }
  __syncthreads();
  float bmx[4], zz[4], ee[4];
#pragma unroll
  for (int r = 0; r < 4; ++r) {
    const int row_l = cg * 4 + r;
    bmx[r] = fmaxf(fmaxf(red[0][0][row_l], red[1][0][row_l]),
                   fmaxf(red[2][0][row_l], red[3][0][row_l]));
    float z = 0.f, e = 0.f;
#pragma unroll
    for (int tg = 0; tg < 16; ++tg) {
      float tt = accs[tg][r] - bmx[r];
      float ex = __expf(tt);
      z += ex;
      e = fmaf(ex, fmaxf(tt, -88.0f), e);
      accs[tg][r] = ex;
    }
    zz[r] = z;
    ee[r] = e;
  }
#pragma unroll
  for (int r = 0; r < 4; ++r) {
#pragma unroll
    for (int o = 1; o < 16; o <<= 1) {
      zz[r] += __shfl_xor(zz[r], o, 64);
      ee[r] += __shfl_xor(ee[r], o, 64);
    }
  }
  __syncthreads();
  if (cl == 0) {
#pragma unroll
    for (int r = 0; r < 4; ++r) {
      red[w][1][cg * 4 + r] = zz[r];
      red[w][2][cg * 4 + r] = ee[r];
    }
  }
  __syncthreads();
#pragma unroll
  for (int r = 0; r < 4; ++r) {
    const int row_l = cg * 4 + r;
    const int l = lb * 16 + row_l;
    float Z = red[0][1][row_l] + red[1][1][row_l] + red[2][1][row_l] + red[3][1][row_l];
    float E = red[0][2][row_l] + red[1][2][row_l] + red[2][2][row_l] + red[3][2][row_l];
    const float rz = __fdividef(1.0f, Z);
    float* ab = out + OFF_ATT + (((size_t)b * HN + h) * LN + l) * SN;
#pragma unroll
    for (int tg = 0; tg < 16; ++tg) {
      const int s = (tg >> 1) * 128 + w * 32 + (tg & 1) * 16 + cl;
      ab[s] = accs[tg][r] * rz;
    }
    if (w == 0 && cl == 0)
      out[OFF_ENT + ((size_t)b * HN + h) * LN + l] = __logf(Z) - E * rz;
  }
}

__global__ __launch_bounds__(256) void k_pv_fb(const float* __restrict__ val,
                                               const float* __restrict__ att,
                                               float* __restrict__ out) {
  int b, lb;
  decode_block(blockIdx.x, b, lb);
  const int h = blockIdx.y;
  const int tid = threadIdx.x;
  const int w = tid >> 6;
  const int c = tid & 63;
  const int dq = c & 15;
  const int sg = c >> 4;
  const int l = lb * 16 + w * 4;

  const float* ab = att + (((size_t)b * HN + h) * LN + l) * SN;
  const float* vb = val + ((size_t)b * SN * HN + h) * EN + dq * 4;

  float4 acc[4];
#pragma unroll
  for (int r = 0; r < 4; ++r) acc[r] = make_float4(0.f, 0.f, 0.f, 0.f);

  for (int st = 0; st < 256; ++st) {
    int s = st * 4 + sg;
    float4 v4 = *(const float4*)(vb + (size_t)s * (HN * EN));
#pragma unroll
    for (int r = 0; r < 4; ++r) {
      float p = ab[r * SN + s];
      acc[r].x = fmaf(p, v4.x, acc[r].x);
      acc[r].y = fmaf(p, v4.y, acc[r].y);
      acc[r].z = fmaf(p, v4.z, acc[r].z);
      acc[r].w = fmaf(p, v4.w, acc[r].w);
    }
  }
#pragma unroll
  for (int r = 0; r < 4; ++r) {
#pragma unroll
    for (int o = 16; o <= 32; o <<= 1) {
      acc[r].x += __shfl_xor(acc[r].x, o, 64);
      acc[r].y += __shfl_xor(acc[r].y, o, 64);
      acc[r].z += __shfl_xor(acc[r].z, o, 64);
      acc[r].w += __shfl_xor(acc[r].w, o, 64);
    }
  }
  if (c < 16) {
#pragma unroll
    for (int r = 0; r < 4; ++r)
      *(float4*)(out + (((size_t)b * LN + l + r) * HN + h) * EN + c * 4) = acc[r];
  }
}

extern "C" void kernel_launch(void* const* d_in, const int* in_sizes, int n_in,
                              void* d_out, int out_size, void* d_ws, size_t ws_size,
                              hipStream_t stream) {
  (void)in_sizes; (void)n_in; (void)out_size;
  const float* q   = (const float*)d_in[0];
  const float* k   = (const float*)d_in[1];
  const float* v   = (const float*)d_in[2];
  const float* pos = (const float*)d_in[3];
  const float* phi = (const float*)d_in[4];
  const float* u   = (const float*)d_in[5];
  const float* lt  = (const float*)d_in[6];
  const float* th  = (const float*)d_in[7];
  const int*   cm  = (const int*)d_in[8];
  float* out = (float*)d_out;

  dim3 grid(256, 8, 1), blk(256, 1, 1);

  if (ws_size >= (size_t)WS_NEED) {
    float* mw = (float*)((char*)d_ws + WS_MASK);
    unsigned short* khi = (unsigned short*)((char*)d_ws + WS_KHI);
    unsigned short* klo = (unsigned short*)((char*)d_ws + WS_KLO);
    unsigned short* vT  = (unsigned short*)((char*)d_ws + WS_VT);
    k_mask_prep<<<dim3(8192), blk, 0, stream>>>(phi, u, lt, th, mw);
    k_kprep<<<dim3(1024), blk, 0, stream>>>(k, khi, klo);
    k_vprep<<<dim3(1024), blk, 0, stream>>>(v, vT);
    k_scores2<<<grid, blk, 0, stream>>>(q, khi, klo, mw, pos, cm, out);
    k_pv2<<<grid, blk, 0, stream>>>(out + OFF_ATT, vT, out);
  } else {
    k_scores_fb<<<grid, blk, 0, stream>>>(q, k, pos, phi, u, lt, th, cm, out);
    k_pv_fb<<<grid, blk, 0, stream>>>(v, out + OFF_ATT, out);
  }
}

// Round 5
// 158.527 us; speedup vs baseline: 2.5974x; 1.6447x over previous
//
#include <hip/hip_runtime.h>

#define BN 4
#define LN 1024
#define SN 1024
#define HN 8
#define EN 64
#define OFF_ATT (BN * LN * HN * EN)
#define OFF_ENT (OFF_ATT + BN * HN * LN * SN)

// workspace byte offsets (ws_size proven >= 46MB in R3; we need 40MB)
#define WS_MASK 0u
#define WS_KB   33554432u                 // 8*1024*1024*4
#define WS_VT   (WS_KB + 4194304u)        // 4*8*1024*64*2
#define WS_NEED (WS_VT + 4194304u)

typedef __attribute__((ext_vector_type(8))) __bf16 bf16x8;
typedef __attribute__((ext_vector_type(4))) float f32x4;
typedef __attribute__((ext_vector_type(4))) unsigned int uint4v;
typedef __attribute__((ext_vector_type(2))) unsigned int uint2v;

// blockIdx.x encodes (lbHi, b, lbLo): batch-siblings of an (h,l-tile) are 8
// blocks apart -> same XCD under round-robin -> shared mask slices L2-hot.
__device__ __forceinline__ void decode_block(int x, int& b, int& lb) {
  int lbLo = x & 7;
  b = (x >> 3) & 3;
  lb = (x >> 5) * 8 + lbLo;
}

// 8 consecutive floats -> packed bf16 hi + lo (trunc split)
__device__ __forceinline__ void cvt8(const float* p, uint4v& hv, uint4v& lv) {
  float4 a = *(const float4*)p;
  float4 bq = *(const float4*)(p + 4);
  float x[8] = {a.x, a.y, a.z, a.w, bq.x, bq.y, bq.z, bq.w};
  unsigned int h[8], lo[8];
#pragma unroll
  for (int i = 0; i < 8; ++i) {
    unsigned int ub = __float_as_uint(x[i]);
    h[i] = ub >> 16;
    float lf = x[i] - __uint_as_float(ub & 0xffff0000u);
    lo[i] = __float_as_uint(lf) >> 16;
  }
  hv = uint4v{h[0] | (h[1] << 16), h[2] | (h[3] << 16),
              h[4] | (h[5] << 16), h[6] | (h[7] << 16)};
  lv = uint4v{lo[0] | (lo[1] << 16), lo[2] | (lo[3] << 16),
              lo[4] | (lo[5] << 16), lo[6] | (lo[7] << 16)};
}

__device__ __forceinline__ uint4v pack8_trunc(float4 a, float4 b) {
  return uint4v{(__float_as_uint(a.x) >> 16) | (__float_as_uint(a.y) & 0xffff0000u),
                (__float_as_uint(a.z) >> 16) | (__float_as_uint(a.w) & 0xffff0000u),
                (__float_as_uint(b.x) >> 16) | (__float_as_uint(b.y) & 0xffff0000u),
                (__float_as_uint(b.z) >> 16) | (__float_as_uint(b.w) & 0xffff0000u)};
}

// ---------------- prep kernels ----------------

// phi-mask: pm = -10000*relu(thr - sigmoid((gumbel+phi)/tau)) * 0.125, fp32
__global__ __launch_bounds__(256) void k_mask_prep(
    const float* __restrict__ phi, const float* __restrict__ u,
    const float* __restrict__ p_logtau, const float* __restrict__ p_thresh,
    float* __restrict__ mw) {
  const float tau = fminf(fmaxf(__expf(p_logtau[0]), 0.1f), 5.0f);
  const float rtau = 1.0f / tau;
  const float thr = fminf(fmaxf(p_thresh[0], 0.01f), 0.99f);
  int idx = (blockIdx.x * 256 + threadIdx.x) * 4;
  float4 u4 = *(const float4*)(u + idx);
  float4 p4 = *(const float4*)(phi + idx);
  float r[4];
  float uu[4] = {u4.x, u4.y, u4.z, u4.w};
  float pp[4] = {p4.x, p4.y, p4.z, p4.w};
#pragma unroll
  for (int i = 0; i < 4; ++i) {
    float g = __logf(__fdividef(uu[i] + 1e-8f, 1.0f - uu[i] + 1e-8f));
    float z = (g + pp[i]) * rtau;
    float sig = __fdividef(1.0f, 1.0f + __expf(-z));
    r[i] = -10000.0f * fmaxf(thr - sig, 0.0f) * 0.125f;
  }
  *(float4*)(mw + idx) = float4{r[0], r[1], r[2], r[3]};
}

// K [b,s,h,e] fp32 -> kb [b][h][s][e] bf16 (single, truncation)
__global__ __launch_bounds__(256) void k_kprep(const float* __restrict__ kk,
                                               unsigned short* __restrict__ kb) {
  int gid = blockIdx.x * 256 + threadIdx.x;  // 262144 groups of 8 elements
  int e8 = gid & 7;
  int tmp = gid >> 3;
  int h = tmp & 7;
  int bs = tmp >> 3;
  int s = bs & 1023;
  int b = bs >> 10;
  const float* src = kk + (size_t)gid * 8;
  float4 a = *(const float4*)src;
  float4 bq = *(const float4*)(src + 4);
  *(uint4v*)(kb + (((size_t)(b * 8 + h) * 1024 + s) * 64) + e8 * 8) =
      pack8_trunc(a, bq);
}

// V [b,s,h,e] fp32 -> vT [b][h][e][s] bf16 (transpose)
__global__ __launch_bounds__(256) void k_vprep(const float* __restrict__ vv,
                                               unsigned short* __restrict__ vT) {
  int gid = blockIdx.x * 256 + threadIdx.x;  // 262144 groups of 8 s
  int s8 = gid & 127;
  int t1 = gid >> 7;
  int e = t1 & 63;
  int t2 = t1 >> 6;
  int h = t2 & 7;
  int b = t2 >> 3;
  float x[8];
#pragma unroll
  for (int j = 0; j < 8; ++j)
    x[j] = vv[((size_t)(b * 1024 + s8 * 8 + j) * 8 + h) * 64 + e];
  uint4v pv = pack8_trunc(float4{x[0], x[1], x[2], x[3]},
                          float4{x[4], x[5], x[6], x[7]});
  *(uint4v*)(vT + ((size_t)(b * 8 + h) * 64 + e) * 1024 + s8 * 8) = pv;
}

// ---------------- fused scores + softmax + entropy + PV ----------------
// Block = 4 waves, 16 q-rows of one (b,h). Swapped QK^T (D = K*Q): lane
// (cl,cg) owns q-row l=lb*16+cl, s = wbase + tg*16 + cg*4 .. +3.
// Wave w owns s-range [w*256, w*256+256). Q hi/lo split, K single bf16.
// PV: att packed bf16 into per-wave swizzled LDS, mfma(vT, att) ->
// out^T[e,l]; cross-wave partial reduce via reused LDS.
__global__ __launch_bounds__(256, 3) void k_fused(
    const float* __restrict__ q, const unsigned short* __restrict__ kb,
    const unsigned short* __restrict__ vT, const float* __restrict__ mw,
    const float* __restrict__ pos, const int* __restrict__ p_causal,
    float* __restrict__ out) {
  int b, lb;
  decode_block(blockIdx.x, b, lb);
  const int h = blockIdx.y;
  const int tid = threadIdx.x;
  const int w = __builtin_amdgcn_readfirstlane(tid >> 6);
  const int c = tid & 63;
  const int cl = c & 15;
  const int cg = c >> 4;

  // per-wave att tile: 16 rows x 256 s, bf16, row=512B, XOR-swizzled.
  __shared__ __align__(16) unsigned char lds_att[4 * 8192];
  __shared__ float red0[4][16], redZ[4][16], redE[4][16];

  const int causal = p_causal[0];
  const int l = lb * 16 + cl;  // this lane's q-row

  // Q fragments (B operand): n = cl (q-row), k = cg*8+j within 32-chunk
  uint4v qh[2], ql[2];
#pragma unroll
  for (int cc = 0; cc < 2; ++cc) {
    const float* qp = q + (((size_t)b * LN + l) * HN + h) * EN + cc * 32 + cg * 8;
    cvt8(qp, qh[cc], ql[cc]);
  }

  const unsigned short* kbb = kb + ((size_t)(b * 8 + h) * 1024) * 64;
  f32x4 accs[16];

  // ---- QK^T: batches of 4 tiles -> 8 loads in flight, then 16 MFMAs
#pragma unroll
  for (int tgb = 0; tgb < 4; ++tgb) {
    uint4v kf[4][2];
#pragma unroll
    for (int t2 = 0; t2 < 4; ++t2) {
      const int row = w * 256 + (tgb * 4 + t2) * 16 + cl;
#pragma unroll
      for (int cc = 0; cc < 2; ++cc)
        kf[t2][cc] = *(const uint4v*)(kbb + (size_t)row * 64 + cc * 32 + cg * 8);
    }
#pragma unroll
    for (int t2 = 0; t2 < 4; ++t2) {
      f32x4 acc = f32x4{0.f, 0.f, 0.f, 0.f};
#pragma unroll
      for (int cc = 0; cc < 2; ++cc) {
        bf16x8 kv = __builtin_bit_cast(bf16x8, kf[t2][cc]);
        acc = __builtin_amdgcn_mfma_f32_16x16x32_bf16(
            kv, __builtin_bit_cast(bf16x8, qh[cc]), acc, 0, 0, 0);
        acc = __builtin_amdgcn_mfma_f32_16x16x32_bf16(
            kv, __builtin_bit_cast(bf16x8, ql[cc]), acc, 0, 0, 0);
      }
      accs[tgb * 4 + t2] = acc;
    }
  }

  // ---- mask + softmax + entropy
  const float* posb = pos + b * LN;
  const float plr = posb[l];
  const float* mrow = mw + ((size_t)h * LN + l) * SN;

  float mx = -3.0e38f;
#pragma unroll
  for (int tg = 0; tg < 16; ++tg) {
    const int s0 = w * 256 + tg * 16 + cg * 4;
    float4 pm4 = *(const float4*)(mrow + s0);
    float4 po4 = *(const float4*)(posb + s0);
    float pmv[4] = {pm4.x, pm4.y, pm4.z, pm4.w};
    float pov[4] = {po4.x, po4.y, po4.z, po4.w};
#pragma unroll
    for (int r = 0; r < 4; ++r) {
      float v = fmaf(accs[tg][r], 0.125f, pmv[r]);
      bool maskd = (causal != 0) && (pov[r] > plr);
      v = maskd ? -1.0e30f : v;
      accs[tg][r] = v;
      mx = fmaxf(mx, v);
    }
  }
  mx = fmaxf(mx, __shfl_xor(mx, 16, 64));
  mx = fmaxf(mx, __shfl_xor(mx, 32, 64));
  if (cg == 0) red0[w][cl] = mx;
  __syncthreads();
  const float bmx = fmaxf(fmaxf(red0[0][cl], red0[1][cl]),
                          fmaxf(red0[2][cl], red0[3][cl]));

  float zz = 0.f, ee = 0.f;
#pragma unroll
  for (int tg = 0; tg < 16; ++tg) {
#pragma unroll
    for (int r = 0; r < 4; ++r) {
      float tt = accs[tg][r] - bmx;
      float ex = __expf(tt);
      zz += ex;
      ee = fmaf(ex, fmaxf(tt, -88.0f), ee);  // guard 0 * -1e30
      accs[tg][r] = ex;
    }
  }
  zz += __shfl_xor(zz, 16, 64);
  zz += __shfl_xor(zz, 32, 64);
  ee += __shfl_xor(ee, 16, 64);
  ee += __shfl_xor(ee, 32, 64);
  if (cg == 0) { redZ[w][cl] = zz; redE[w][cl] = ee; }
  __syncthreads();
  const float Z = redZ[0][cl] + redZ[1][cl] + redZ[2][cl] + redZ[3][cl];
  const float E = redE[0][cl] + redE[1][cl] + redE[2][cl] + redE[3][cl];
  const float rz = __fdividef(1.0f, Z);

  // ---- att store (global fp32) + packed bf16 into swizzled per-wave LDS
  float* ab = out + OFF_ATT + (((size_t)b * HN + h) * LN + l) * SN;
  unsigned char* arow = lds_att + w * 8192 + cl * 512;
  const int rsw = (cl & 7) << 4;
#pragma unroll
  for (int tg = 0; tg < 16; ++tg) {
    const int s0 = w * 256 + tg * 16 + cg * 4;
    float4 av = float4{accs[tg][0] * rz, accs[tg][1] * rz,
                       accs[tg][2] * rz, accs[tg][3] * rz};
    *(float4*)(ab + s0) = av;
    uint2v pk = uint2v{
        (__float_as_uint(av.x) >> 16) | (__float_as_uint(av.y) & 0xffff0000u),
        (__float_as_uint(av.z) >> 16) | (__float_as_uint(av.w) & 0xffff0000u)};
    *(uint2v*)(arow + ((tg * 32 + cg * 8) ^ rsw)) = pk;
  }
  if (w == 0 && cg == 0)
    out[OFF_ENT + ((size_t)b * HN + h) * LN + l] = __logf(Z) - E * rz;

  // ---- PV: no barrier needed (wave reads only its own att region).
  // A = vT frag (m=e-in-tile=cl, k=cg*8+j), B = att frag (n=l=cl, k=cg*8+j)
  const unsigned short* vbb = vT + ((size_t)(b * 8 + h) * 64) * 1024;
  f32x4 pv[4];
#pragma unroll
  for (int et = 0; et < 4; ++et) pv[et] = f32x4{0.f, 0.f, 0.f, 0.f};

#pragma unroll
  for (int kcb = 0; kcb < 4; ++kcb) {
    uint4v af[2], vf[2][4];
#pragma unroll
    for (int k2 = 0; k2 < 2; ++k2) {
      const int kc = kcb * 2 + k2;
      af[k2] = *(const uint4v*)(arow + ((kc * 64 + cg * 16) ^ rsw));
#pragma unroll
      for (int et = 0; et < 4; ++et)
        vf[k2][et] = *(const uint4v*)(vbb + ((size_t)(et * 16 + cl)) * 1024 +
                                      w * 256 + kc * 32 + cg * 8);
    }
#pragma unroll
    for (int k2 = 0; k2 < 2; ++k2) {
      bf16x8 batt = __builtin_bit_cast(bf16x8, af[k2]);
#pragma unroll
      for (int et = 0; et < 4; ++et)
        pv[et] = __builtin_amdgcn_mfma_f32_16x16x32_bf16(
            __builtin_bit_cast(bf16x8, vf[k2][et]), batt, pv[et], 0, 0, 0);
    }
  }

  // ---- cross-wave reduce of PV partials (reuse lds_att; stride 272B)
  __syncthreads();  // all waves done reading their att regions
#pragma unroll
  for (int et = 0; et < 4; ++et)
    *(f32x4*)(lds_att + w * 4352 + cl * 272 + et * 64 + cg * 16) = pv[et];
  __syncthreads();
  {
    const int lr = tid >> 4;       // 0..15
    const int e0 = (tid & 15) * 4; // 0..60
    f32x4 s0 = *(const f32x4*)(lds_att + 0 * 4352 + lr * 272 + e0 * 4);
    f32x4 s1 = *(const f32x4*)(lds_att + 1 * 4352 + lr * 272 + e0 * 4);
    f32x4 s2 = *(const f32x4*)(lds_att + 2 * 4352 + lr * 272 + e0 * 4);
    f32x4 s3 = *(const f32x4*)(lds_att + 3 * 4352 + lr * 272 + e0 * 4);
    f32x4 sum = s0 + s1 + s2 + s3;
    *(f32x4*)(out + (((size_t)b * LN + lb * 16 + lr) * HN + h) * EN + e0) = sum;
  }
}

extern "C" void kernel_launch(void* const* d_in, const int* in_sizes, int n_in,
                              void* d_out, int out_size, void* d_ws, size_t ws_size,
                              hipStream_t stream) {
  (void)in_sizes; (void)n_in; (void)out_size; (void)ws_size;
  const float* q   = (const float*)d_in[0];
  const float* k   = (const float*)d_in[1];
  const float* v   = (const float*)d_in[2];
  const float* pos = (const float*)d_in[3];
  const float* phi = (const float*)d_in[4];
  const float* u   = (const float*)d_in[5];
  const float* lt  = (const float*)d_in[6];
  const float* th  = (const float*)d_in[7];
  const int*   cm  = (const int*)d_in[8];
  float* out = (float*)d_out;

  float* mw = (float*)((char*)d_ws + WS_MASK);
  unsigned short* kb = (unsigned short*)((char*)d_ws + WS_KB);
  unsigned short* vT = (unsigned short*)((char*)d_ws + WS_VT);

  dim3 blk(256, 1, 1);
  k_mask_prep<<<dim3(8192), blk, 0, stream>>>(phi, u, lt, th, mw);
  k_kprep<<<dim3(1024), blk, 0, stream>>>(k, kb);
  k_vprep<<<dim3(1024), blk, 0, stream>>>(v, vT);
  k_fused<<<dim3(256, 8, 1), blk, 0, stream>>>(q, kb, vT, mw, pos, cm, out);
}